// Round 5
// baseline (175.512 us; speedup 1.0000x reference)
//
#include <hip/hip_runtime.h>
#include <hip/hip_bf16.h>
#include <stdint.h>

#define B_ 2
#define S_ 2048
#define H_ 32
#define D_ 128
#define R_ (B_*H_*S_)   // 131072 rows per tensor (head-major); also = total q-rows
#define QKBLKS (2 * R_ / 8)
#define VSBLKS (R_ / 4)
#define NDBLKS (2 * R_ / 256)   // zero num+den (2*131072 floats)

typedef __bf16 bf16x8 __attribute__((ext_vector_type(8)));
typedef float  f32x16 __attribute__((ext_vector_type(16)));

#if __has_builtin(__builtin_amdgcn_exp2f)
#define EXP2F(x) __builtin_amdgcn_exp2f(x)
#else
#define EXP2F(x) exp2f(x)
#endif

__device__ __forceinline__ unsigned short f2bf(float f) {
  unsigned u = __float_as_uint(f);
  u += 0x7FFFu + ((u >> 16) & 1u);
  return (unsigned short)(u >> 16);
}

// Fused prep: [0,QKBLKS): q,k [B,S,H,D] fp32 -> [B,H,S,D] bf16 (Q gets
// scale*log2e folded); [QKBLKS,+VSBLKS): vsum[b,h,s]=sum_d v; rest: zero nd.
__global__ __launch_bounds__(256) void prep(
    const float* __restrict__ q, const float* __restrict__ k,
    const float* __restrict__ v,
    unsigned short* __restrict__ qb, unsigned short* __restrict__ kb,
    float* __restrict__ vsum, float* __restrict__ nd, float* __restrict__ out0) {
  const int bid = blockIdx.x;
  const int t = threadIdx.x;
  if (bid == 0 && t == 0) out0[0] = 0.f;
  if (bid < QKBLKS) {
    const int rowblk = bid * 8 + (t >> 5);
    const float* src; unsigned short* dst; int r; float sc;
    if (rowblk < R_) { src = q; dst = qb; r = rowblk; sc = 0.0883883476483184f * 1.4426950408889634f; }
    else             { src = k; dst = kb; r = rowblk - R_; sc = 1.0f; }
    const int b  = r / (H_ * S_);
    const int hs = r % (H_ * S_);
    const int h  = hs / S_;
    const int s  = hs % S_;
    const size_t inoff = (((size_t)b * S_ + s) * H_ + h) * D_;
    const int lane32 = t & 31;
    const float4 v4 = *reinterpret_cast<const float4*>(src + inoff + lane32 * 4);
    ushort4 o;
    o.x = f2bf(v4.x * sc); o.y = f2bf(v4.y * sc); o.z = f2bf(v4.z * sc); o.w = f2bf(v4.w * sc);
    *reinterpret_cast<ushort4*>(dst + (size_t)r * D_ + lane32 * 4) = o;
  } else if (bid < QKBLKS + VSBLKS) {
    const int r = (bid - QKBLKS) * 4 + (t >> 6);
    const int lane = t & 63;
    const int b  = r / (H_ * S_);
    const int hs = r % (H_ * S_);
    const int h  = hs / S_;
    const int s  = hs % S_;
    const size_t inoff = (((size_t)b * S_ + s) * H_ + h) * D_;
    const float2 x = *reinterpret_cast<const float2*>(v + inoff + lane * 2);
    float sum = x.x + x.y;
    #pragma unroll
    for (int m = 1; m < 64; m <<= 1) sum += __shfl_xor(sum, m);
    if (lane == 0) vsum[r] = sum;
  } else {
    nd[(size_t)(bid - QKBLKS - VSBLKS) * 256 + t] = 0.f;
  }
}

// Main: block = (bh, 64-row k-block). Each wave holds the ENTIRE K-block in
// registers as MFMA A-frags (+ per-lane vsum weights) and streams q-tiles:
// sacc = mfma(K, Q) puts k on accumulator ROWS and q on COLUMNS, so each lane
// accumulates (num,den) for exactly one q-column -> no cross-lane reduction,
// no LDS, no barriers. Partials combine via fp32 global atomics.
// id mapping: id % 8 == bh % 8  => all 32 blocks of a bh (and its 512KB
// Q-tile) land on one XCD -> Q streams from that XCD's L2.
__global__ __launch_bounds__(256, 3) void attn_sum(
    const unsigned short* __restrict__ qg_, const unsigned short* __restrict__ kg_,
    const float* __restrict__ vsum, float* __restrict__ numb,
    float* __restrict__ denb) {
  const int id  = blockIdx.x;
  const int bh  = (id & 7) + 8 * (id >> 8);
  const int kbi = (id >> 3) & 31;
  const int kb  = (kbi & 1) ? (31 - (kbi >> 1)) : (kbi >> 1);  // heavy/light mix
  const int kbase = kb * 64;

  const int t = threadIdx.x;
  const int w = t >> 6;
  const int l = t & 63;
  const int ln = l & 31, l5 = l >> 5;

  const size_t base = (size_t)bh * S_ * D_;

  // Resident K: A-frags (m = k-row = lane&31, k-dim = d-chunk c*16 + l5*8).
  bf16x8 kf[2][8];
  {
    const unsigned short* kp = kg_ + base + (size_t)(kbase + ln) * D_ + l5 * 8;
    #pragma unroll
    for (int nb = 0; nb < 2; ++nb)
      #pragma unroll
      for (int c = 0; c < 8; ++c)
        kf[nb][c] = *reinterpret_cast<const bf16x8*>(kp + (nb * 32) * D_ + c * 16);
  }

  // Resident vsum weights for this block's k-rows, in C/D register order:
  // row(r) = (r&3) + 8*(r>>2) + 4*l5.
  float vsv[2][16];
  {
    const float* vp = vsum + (size_t)bh * S_ + kbase + l5 * 4;
    #pragma unroll
    for (int nb = 0; nb < 2; ++nb)
      #pragma unroll
      for (int g = 0; g < 4; ++g) {
        const float4 vv = *reinterpret_cast<const float4*>(vp + nb * 32 + g * 8);
        vsv[nb][g * 4 + 0] = vv.x; vsv[nb][g * 4 + 1] = vv.y;
        vsv[nb][g * 4 + 2] = vv.z; vsv[nb][g * 4 + 3] = vv.w;
      }
  }

  float* nrow = numb + (size_t)bh * S_;
  float* drow = denb + (size_t)bh * S_;

  for (int qt = kb >> 1; qt < 16; ++qt) {
    const int qmin = qt * 128 + w * 32;        // this wave's 32 q-cols
    if (kbase > qmin + 31) continue;           // wave-uniform causal skip

    // Stream Q: B-frags (n = q-col = lane&31, k-dim = d-chunk c*16 + l5*8).
    bf16x8 qf[8];
    const unsigned short* qp = qg_ + base + (size_t)(qmin + ln) * D_ + l5 * 8;
    #pragma unroll
    for (int c = 0; c < 8; ++c)
      qf[c] = *reinterpret_cast<const bf16x8*>(qp + c * 16);

    float np = 0.f, dp = 0.f;
    #pragma unroll
    for (int nb = 0; nb < 2; ++nb) {
      const int kb0 = kbase + nb * 32;
      if (kb0 > qmin + 31) continue;           // upper half fully masked
      f32x16 sacc = {0.f,0.f,0.f,0.f,0.f,0.f,0.f,0.f,
                     0.f,0.f,0.f,0.f,0.f,0.f,0.f,0.f};
      __builtin_amdgcn_s_setprio(1);
      #pragma unroll
      for (int c = 0; c < 8; ++c)
        sacc = __builtin_amdgcn_mfma_f32_32x32x16_bf16(kf[nb][c], qf[c], sacc, 0, 0, 0);
      __builtin_amdgcn_s_setprio(0);
      if (kb0 + 31 <= qmin) {
        // interior: no mask
        #pragma unroll
        for (int r = 0; r < 16; ++r) {
          const float e = EXP2F(sacc[r]);
          dp += e;
          np = fmaf(e, vsv[nb][r], np);
        }
      } else {
        // diagonal: per-element causal mask (k-row from C/D layout)
        const int qg = qmin + ln;
        #pragma unroll
        for (int r = 0; r < 16; ++r) {
          const int kg = kb0 + (r & 3) + 8 * (r >> 2) + 4 * l5;
          const float e = (kg <= qg) ? EXP2F(sacc[r]) : 0.f;
          dp += e;
          np = fmaf(e, vsv[nb][r], np);
        }
      }
    }
    // Combine the two l5 halves (same q-col, different k-rows), then one
    // atomic pair per q-col.
    np += __shfl_xor(np, 32);
    dp += __shfl_xor(dp, 32);
    if (l5 == 0) {
      atomicAdd(&nrow[qmin + ln], np);
      atomicAdd(&drow[qmin + ln], dp);
    }
  }
}

// Finalize: sum(num/den) over all q-rows.
__global__ __launch_bounds__(256) void finalize(
    const float* __restrict__ numb, const float* __restrict__ denb,
    float* __restrict__ out) {
  const int i = blockIdx.x * 256 + threadIdx.x;
  float c = numb[i] / denb[i];
  #pragma unroll
  for (int m = 1; m < 64; m <<= 1) c += __shfl_xor(c, m);
  __shared__ float ps[4];
  if ((threadIdx.x & 63) == 0) ps[threadIdx.x >> 6] = c;
  __syncthreads();
  if (threadIdx.x == 0) atomicAdd(out, ps[0] + ps[1] + ps[2] + ps[3]);
}

extern "C" void kernel_launch(void* const* d_in, const int* in_sizes, int n_in,
                              void* d_out, int out_size, void* d_ws, size_t ws_size,
                              hipStream_t stream) {
  const float* q = (const float*)d_in[0];
  const float* k = (const float*)d_in[1];
  const float* v = (const float*)d_in[2];
  float* out = (float*)d_out;

  unsigned short* qb = (unsigned short*)d_ws;                 // 33.5 MiB
  unsigned short* kb = qb + (size_t)R_ * D_;                  // 33.5 MiB
  float* vsum = (float*)(kb + (size_t)R_ * D_);               // 512 KiB
  float* numb = vsum + R_;                                    // 512 KiB
  float* denb = numb + R_;                                    // 512 KiB

  hipLaunchKernelGGL(prep, dim3(QKBLKS + VSBLKS + NDBLKS), dim3(256), 0, stream,
                     q, k, v, qb, kb, vsum, numb, out);
  hipLaunchKernelGGL(attn_sum, dim3(2048), dim3(256), 0, stream,
                     qb, kb, vsum, numb, denb);
  hipLaunchKernelGGL(finalize, dim3(R_ / 256), dim3(256), 0, stream,
                     numb, denb, out);
}

// Round 6
// 130.870 us; speedup vs baseline: 1.3411x; 1.3411x over previous
//
#include <hip/hip_runtime.h>
#include <hip/hip_bf16.h>
#include <stdint.h>

#define B_ 2
#define S_ 2048
#define H_ 32
#define D_ 128
#define R_ (B_*H_*S_)   // 131072 rows per tensor (head-major)
#define QKBLKS (2 * R_ / 8)
#define VSBLKS (R_ / 4)
#define NDBLKS (2 * R_ / 256)   // zero num+den
#define CPB 40                  // uniform k-chunks per bh

typedef __bf16 bf16x8 __attribute__((ext_vector_type(8)));
typedef float  f32x16 __attribute__((ext_vector_type(16)));

#if __has_builtin(__builtin_amdgcn_exp2f)
#define EXP2F(x) __builtin_amdgcn_exp2f(x)
#else
#define EXP2F(x) exp2f(x)
#endif

#define AS1 __attribute__((address_space(1)))
#define AS3 __attribute__((address_space(3)))

__device__ __forceinline__ unsigned short f2bf(float f) {
  unsigned u = __float_as_uint(f);
  u += 0x7FFFu + ((u >> 16) & 1u);
  return (unsigned short)(u >> 16);
}

// Fused prep: [0,QKBLKS): q,k [B,S,H,D] fp32 -> [B,H,S,D] bf16 (Q gets
// scale*log2e folded); [+VSBLKS): vsum[b,h,s]=sum_d v; rest: zero num/den.
__global__ __launch_bounds__(256) void prep(
    const float* __restrict__ q, const float* __restrict__ k,
    const float* __restrict__ v,
    unsigned short* __restrict__ qb, unsigned short* __restrict__ kb,
    float* __restrict__ vsum, float* __restrict__ nd, float* __restrict__ out0) {
  const int bid = blockIdx.x;
  const int t = threadIdx.x;
  if (bid == 0 && t == 0) out0[0] = 0.f;
  if (bid < QKBLKS) {
    const int rowblk = bid * 8 + (t >> 5);
    const float* src; unsigned short* dst; int r; float sc;
    if (rowblk < R_) { src = q; dst = qb; r = rowblk; sc = 0.0883883476483184f * 1.4426950408889634f; }
    else             { src = k; dst = kb; r = rowblk - R_; sc = 1.0f; }
    const int b  = r / (H_ * S_);
    const int hs = r % (H_ * S_);
    const int h  = hs / S_;
    const int s  = hs % S_;
    const size_t inoff = (((size_t)b * S_ + s) * H_ + h) * D_;
    const int lane32 = t & 31;
    const float4 v4 = *reinterpret_cast<const float4*>(src + inoff + lane32 * 4);
    ushort4 o;
    o.x = f2bf(v4.x * sc); o.y = f2bf(v4.y * sc); o.z = f2bf(v4.z * sc); o.w = f2bf(v4.w * sc);
    *reinterpret_cast<ushort4*>(dst + (size_t)r * D_ + lane32 * 4) = o;
  } else if (bid < QKBLKS + VSBLKS) {
    const int r = (bid - QKBLKS) * 4 + (t >> 6);
    const int lane = t & 63;
    const int b  = r / (H_ * S_);
    const int hs = r % (H_ * S_);
    const int h  = hs / S_;
    const int s  = hs % S_;
    const size_t inoff = (((size_t)b * S_ + s) * H_ + h) * D_;
    const float2 x = *reinterpret_cast<const float2*>(v + inoff + lane * 2);
    float sum = x.x + x.y;
    #pragma unroll
    for (int m = 1; m < 64; m <<= 1) sum += __shfl_xor(sum, m);
    if (lane == 0) vsum[r] = sum;
  } else {
    nd[(size_t)(bid - QKBLKS - VSBLKS) * 256 + t] = 0.f;
  }
}

// Main: block = (bh, qt 128 q-rows, uniform k-chunk of <=8 64-row k-tiles).
// R4's proven pipeline: fragment-major global_load_lds staging (bank-optimal
// ds_read_b128, one addr + imm offsets), depth-1 double buffer,
// {vmcnt(0); barrier; stage(next); compute(cur)} per tile. Uniform work per
// block (2560 blocks, 2.5x oversubscribed) keeps occupancy pegged; partial
// (num,den) per q-row merged via fp32 global atomics.
__global__ __launch_bounds__(256, 4) void attn_sum(
    const unsigned short* __restrict__ qg_, const unsigned short* __restrict__ kg_,
    const float* __restrict__ vsum, float* __restrict__ numb,
    float* __restrict__ denb) {
  __shared__ uint4 kbuf[2][1024];      // 2 x 16KB
  __shared__ float vsbuf[2][64];       // 2 x 256B

  // id -> (bh, chunk c): same-bh blocks share id%8 -> likely same XCD.
  const int id = blockIdx.x;
  const int y  = id >> 3;
  const int bh = (id & 7) + 8 * (y / CPB);
  const int c  = y % CPB;

  // chunk table: qt 0-3 -> 1 chunk; 4-7 -> 2; 8-11 -> 3; 12-15 -> 4.
  int qt, h, nch;
  if (c < 4)       { qt = c;                 h = 0;            nch = 1; }
  else if (c < 12) { qt = 4 + ((c - 4) >> 1);  h = (c - 4) & 1;  nch = 2; }
  else if (c < 24) { qt = 8 + (c - 12) / 3;    h = (c - 12) % 3; nch = 3; }
  else             { qt = 12 + ((c - 24) >> 2); h = (c - 24) & 3; nch = 4; }
  const int nkt  = 2 * qt + 2;
  const int bas_ = nkt / nch, rem = nkt % nch;
  const int kt0  = h * bas_ + (h < rem ? h : rem);
  const int kt1  = kt0 + bas_ + (h < rem ? 1 : 0);

  const int t  = threadIdx.x;
  const int w  = t >> 6;
  const int l  = t & 63;
  const int ln = l & 31, l5 = l >> 5;

  const size_t base = (size_t)bh * S_ * D_;
  const int qrow0 = qt * 128 + w * 32;
  const unsigned short* ksrc0 = kg_ + base;
  const float* vsrc0 = vsum + (size_t)bh * S_;

  // Q A-frags: 32 q-rows (m = lane&31), k-chunk d = kb8*16 + l5*8 .. +8.
  bf16x8 qfrag[8];
  {
    const unsigned short* qp = qg_ + base + (size_t)(qrow0 + ln) * D_ + l5 * 8;
    #pragma unroll
    for (int kb8 = 0; kb8 < 8; ++kb8)
      qfrag[kb8] = *reinterpret_cast<const bf16x8*>(qp + kb8 * 16);
  }

  // Stage one 64-row K-tile (+vsum strip): 5 DMA ops per wave, fragment-major.
  auto stage = [&](int j, int slot) {
    const unsigned short* ksrc = ksrc0 + (size_t)j * 64 * D_;
    #pragma unroll
    for (int i = 0; i < 4; ++i) {
      const int f   = w * 256 + i * 64 + l;      // flat fragment-major chunk id
      const int ln_ = f & 31, l5_ = (f >> 5) & 1;
      const int kb8_ = (f >> 6) & 7, nb_ = (f >> 9) & 1;
      const unsigned short* src = ksrc + (nb_ * 32 + ln_) * D_ + (kb8_ * 2 + l5_) * 8;
      __builtin_amdgcn_global_load_lds(
          (const AS1 void*)src, (AS3 void*)(&kbuf[slot][f & ~63]), 16, 0, 0);
    }
    __builtin_amdgcn_global_load_lds(
        (const AS1 void*)(vsrc0 + j * 64 + l), (AS3 void*)(&vsbuf[slot][0]), 4, 0, 0);
  };

  float num[16], den[16];
  #pragma unroll
  for (int r = 0; r < 16; ++r) { num[r] = 0.f; den[r] = 0.f; }

  stage(kt0, 0);
  int cur = 0;
  for (int kt = kt0; kt < kt1; ++kt) {
    asm volatile("s_waitcnt vmcnt(0)" ::: "memory");
    __syncthreads();
    if (kt + 1 < kt1) stage(kt + 1, cur ^ 1);

    const int ktb = kt * 64;
    if (ktb <= qrow0 + 31) {               // wave-uniform causal skip
      const uint4* tbase = &kbuf[cur][l5 * 32 + ln];   // one addr, imm offsets
      #pragma unroll
      for (int nb = 0; nb < 2; ++nb) {
        const int kbase = ktb + nb * 32;
        if (kbase > qrow0 + 31) continue;
        f32x16 sacc = {0.f,0.f,0.f,0.f,0.f,0.f,0.f,0.f,
                       0.f,0.f,0.f,0.f,0.f,0.f,0.f,0.f};
        __builtin_amdgcn_s_setprio(1);
        #pragma unroll
        for (int kb8 = 0; kb8 < 8; ++kb8) {
          const bf16x8 bf = *reinterpret_cast<const bf16x8*>(&tbase[(nb * 8 + kb8) * 64]);
          sacc = __builtin_amdgcn_mfma_f32_32x32x16_bf16(qfrag[kb8], bf, sacc, 0, 0, 0);
        }
        __builtin_amdgcn_s_setprio(0);
        const float vsv = vsbuf[cur][nb * 32 + ln];
        if (kbase + 31 <= qrow0) {
          #pragma unroll
          for (int r = 0; r < 16; ++r) {
            const float e = EXP2F(sacc[r]);
            den[r] += e;
            num[r] = fmaf(e, vsv, num[r]);
          }
        } else {
          const int kgc = kbase + ln;
          #pragma unroll
          for (int r = 0; r < 16; ++r) {
            const int qgr = qrow0 + (r & 3) + 8 * (r >> 2) + 4 * l5;
            const float e = (kgc <= qgr) ? EXP2F(sacc[r]) : 0.f;
            den[r] += e;
            num[r] = fmaf(e, vsv, num[r]);
          }
        }
      }
    }
    cur ^= 1;
  }

  // Reduce over the 32 k-cols (lanes within each l5 half), then one atomic
  // pair per q-row from lane ln==0 of each half.
  #pragma unroll
  for (int m = 1; m < 32; m <<= 1) {
    #pragma unroll
    for (int r = 0; r < 16; ++r) {
      num[r] += __shfl_xor(num[r], m);
      den[r] += __shfl_xor(den[r], m);
    }
  }
  if (ln == 0) {
    float* nrow = numb + (size_t)bh * S_;
    float* drow = denb + (size_t)bh * S_;
    #pragma unroll
    for (int r = 0; r < 16; ++r) {
      const int qgr = qrow0 + (r & 3) + 8 * (r >> 2) + 4 * l5;
      atomicAdd(&nrow[qgr], num[r]);
      atomicAdd(&drow[qgr], den[r]);
    }
  }
}

// Finalize: sum(num/den) over all q-rows.
__global__ __launch_bounds__(256) void finalize(
    const float* __restrict__ numb, const float* __restrict__ denb,
    float* __restrict__ out) {
  const int i = blockIdx.x * 256 + threadIdx.x;
  float c = numb[i] / denb[i];
  #pragma unroll
  for (int m = 1; m < 64; m <<= 1) c += __shfl_xor(c, m);
  __shared__ float ps[4];
  if ((threadIdx.x & 63) == 0) ps[threadIdx.x >> 6] = c;
  __syncthreads();
  if (threadIdx.x == 0) atomicAdd(out, ps[0] + ps[1] + ps[2] + ps[3]);
}

extern "C" void kernel_launch(void* const* d_in, const int* in_sizes, int n_in,
                              void* d_out, int out_size, void* d_ws, size_t ws_size,
                              hipStream_t stream) {
  const float* q = (const float*)d_in[0];
  const float* k = (const float*)d_in[1];
  const float* v = (const float*)d_in[2];
  float* out = (float*)d_out;

  unsigned short* qb = (unsigned short*)d_ws;                 // 32 MiB
  unsigned short* kb = qb + (size_t)R_ * D_;                  // 32 MiB
  float* vsum = (float*)(kb + (size_t)R_ * D_);               // 512 KiB
  float* numb = vsum + R_;                                    // 512 KiB
  float* denb = numb + R_;                                    // 512 KiB

  hipLaunchKernelGGL(prep, dim3(QKBLKS + VSBLKS + NDBLKS), dim3(256), 0, stream,
                     q, k, v, qb, kb, vsum, numb, out);
  hipLaunchKernelGGL(attn_sum, dim3(64 * CPB), dim3(256), 0, stream,
                     qb, kb, vsum, numb, denb);
  hipLaunchKernelGGL(finalize, dim3(R_ / 256), dim3(256), 0, stream,
                     numb, denb, out);
}